// Round 26
// baseline (283.543 us; speedup 1.0000x reference)
//
#include <hip/hip_runtime.h>
#include <stdint.h>

// Problem constants: B=4, N=32768, K=16, nqueries=2048, stride=16.
//
// ALGORITHMIC CUT (exact): counting-sort points into 256 x-bins, then each
// query (1 per wave, 8192 waves = 8/SIMD) scans only bins with
// min-x-distance <= sqrt(tau): ~2.5-3.5k points instead of 32768 (10-13x
// less gate work, ~33% fewer inserts). Stop rule is strictly conservative
// ((edge-1e-4)^2 > tau with fp-edge error <= 3e-6), and candidates go
// through the EXACT numpy-ordered distance + exact ballot-insert machinery
// (proven bit-exact across 10 passing runs) -> results identical.
// Fallback: R14 brute-force kernel (best measured 141.6 us) if ws small.
#define NPTS  32768
#define NQ    2048
#define KNN   16
#define NB    4
#define NBINS 256
#define XMIN  (-6.0f)
#define XW    (12.0f / NBINS)        // 0.046875, exact in fp32
#define INVXW (NBINS / 12.0f)
#define SAFE  1e-4f
#define GATE_MARGIN 5e-4f            // fallback kernel only

__device__ __forceinline__ int dpp_shr1_i(int x) {
    // row_shr:1 within 16-lane rows; row-start lane keeps old (bound_ctrl=0)
    return __builtin_amdgcn_update_dpp(x, x, 0x111, 0xf, 0xf, false);
}
__device__ __forceinline__ float dpp_shr1_f(float x) {
    return __int_as_float(dpp_shr1_i(__float_as_int(x)));
}
__device__ __forceinline__ float readlane_f(float x, int l) {
    return __int_as_float(__builtin_amdgcn_readlane(__float_as_int(x), l));
}
__device__ __forceinline__ int binof(float x) {
    int b = (int)((x - XMIN) * INVXW);
    return min(max(b, 0), NBINS - 1);
}

// Exact distributed top-16 (list in lanes 0..15, ascending (d,idx); lane 15
// holds exact tau). vm masks out invalid lanes. d is the EXACT numpy distance.
__device__ __forceinline__ void insert16(float d, int p, int lane,
                                         float& ld, int& li, float& tau,
                                         unsigned long long vm)
{
    unsigned long long rem = __ballot(d <= tau) & vm;
    while (rem) {
        const int srcl = __ffsll(rem) - 1;           // wave-uniform
        const float wd = readlane_f(d, srcl);
        const int   wi = __builtin_amdgcn_readlane(p, srcl);
        const bool less = (ld < wd) || (ld == wd && li < wi);
        const unsigned long long lm = __ballot(less);
        const int pos = __popc((unsigned)(lm & 0xffffull));
        const float pld = dpp_shr1_f(ld);
        const int   pli = dpp_shr1_i(li);
        if (lane < 16) {
            if (lane == pos)      { ld = wd;  li = wi;  }
            else if (lane > pos)  { ld = pld; li = pli; }
        }
        tau = readlane_f(ld, 15);
        rem &= rem - 1;
        if (rem) rem &= __ballot(d <= tau);          // re-gate survivors (exact)
    }
}

// ---------------- build phase ----------------
__global__ __launch_bounds__(NBINS) void zero_k(int* __restrict__ cur) {
    cur[blockIdx.x * NBINS + threadIdx.x] = 0;
}

__global__ __launch_bounds__(256) void hist_k(const float* __restrict__ xyz,
                                              int* __restrict__ cur)
{
    const int i = blockIdx.x * 256 + threadIdx.x;    // 0 .. NB*NPTS-1
    const int b = i >> 15;
    const int idx = i & (NPTS - 1);
    const float x = xyz[(size_t)b * NPTS * 3 + 3 * idx];
    atomicAdd(&cur[b * NBINS + binof(x)], 1);
}

__global__ __launch_bounds__(NBINS) void scan_k(int* __restrict__ cur,
                                                int* __restrict__ off)
{
    const int b = blockIdx.x, t = threadIdx.x;
    __shared__ int sh[NBINS];
    const int c = cur[b * NBINS + t];
    sh[t] = c;
    __syncthreads();
    for (int o = 1; o < NBINS; o <<= 1) {
        const int v = (t >= o) ? sh[t - o] : 0;
        __syncthreads();
        sh[t] += v;
        __syncthreads();
    }
    const int excl = sh[t] - c;                      // exclusive prefix
    off[b * (NBINS + 1) + t] = excl;
    if (t == NBINS - 1) off[b * (NBINS + 1) + NBINS] = sh[t];   // = NPTS
    cur[b * NBINS + t] = excl;                       // scatter cursors
}

__global__ __launch_bounds__(256) void scatter_k(const float* __restrict__ xyz,
                                                 int* __restrict__ cur,
                                                 float4* __restrict__ sorted)
{
    const int i = blockIdx.x * 256 + threadIdx.x;
    const int b = i >> 15;
    const int idx = i & (NPTS - 1);
    const size_t a = (size_t)b * NPTS * 3 + 3 * idx;
    const float x = xyz[a], y = xyz[a + 1], z = xyz[a + 2];
    const int pos = atomicAdd(&cur[b * NBINS + binof(x)], 1);
    sorted[(size_t)b * NPTS + pos] = make_float4(x, y, z, __int_as_float(idx));
}

// ---------------- query phase: 1 query per wave ----------------
__device__ __forceinline__ void scan_bin(const float4* __restrict__ sp,
                                         int s, int e, int lane,
                                         float qx, float qy, float qz,
                                         float& ld, int& li, float& tau)
{
    for (int ba = s; ba < e; ba += 64) {
        float d = __builtin_inff(); int pi = 0x7fffffff;
        const unsigned long long vm = __ballot(ba + lane < e);
        if (ba + lane < e) {
            const float4 pt = sp[ba + lane];
            const float dx = __fadd_rn(pt.x, -qx);
            const float dy = __fadd_rn(pt.y, -qy);
            const float dz = __fadd_rn(pt.z, -qz);
            d = __fadd_rn(__fadd_rn(__fmul_rn(dx, dx), __fmul_rn(dy, dy)),
                          __fmul_rn(dz, dz));
            pi = __float_as_int(pt.w);
        }
        insert16(d, pi, lane, ld, li, tau, vm);
    }
}

__global__ __launch_bounds__(256) void knn_grid(const float* __restrict__ xyz,
                                                const float4* __restrict__ sorted,
                                                const int* __restrict__ off,
                                                float* __restrict__ out_idx,
                                                float* __restrict__ out_pts)
{
    const int tid  = threadIdx.x;
    const int lane = tid & 63;
    const int wv   = tid >> 6;
    const int w    = blockIdx.x * 4 + wv;            // 0 .. 8191
    const int b    = w >> 11;
    const int qi   = w & 2047;
    const size_t base3 = (size_t)b * NPTS * 3;
    const int qp = qi << 4;                          // stride-16 subsample
    const float qx = xyz[base3 + 3 * qp + 0];
    const float qy = xyz[base3 + 3 * qp + 1];
    const float qz = xyz[base3 + 3 * qp + 2];

    const int g = b * NQ + qi;
    if (lane == 0) {
        out_pts[3 * g + 0] = qx;
        out_pts[3 * g + 1] = qy;
        out_pts[3 * g + 2] = qz;
    }

    const float4* sp = sorted + (size_t)b * NPTS;
    const int* ofb = off + b * (NBINS + 1);

    float ld = __builtin_inff(); int li = 0x7fffffff;
    float tau = __builtin_inff();

    const int bq = binof(qx);
    scan_bin(sp, ofb[bq], ofb[bq + 1], lane, qx, qy, qz, ld, li, tau);

    int bl = bq - 1, br = bq + 1;
    for (;;) {
        // min x-distance from qx to bins bl / br (exact edge bound; clamped
        // border bins extend outward so edge distance stays valid).
        const float dl = (bl >= 0)     ? (qx - (XMIN + (bl + 1) * XW)) : 1e30f;
        const float dr = (br < NBINS)  ? ((XMIN + br * XW) - qx)       : 1e30f;
        const float dls = dl - SAFE, drs = dr - SAFE;
        const bool doneL = (bl < 0)      || (dls > 0.0f && dls * dls > tau);
        const bool doneR = (br >= NBINS) || (drs > 0.0f && drs * drs > tau);
        if (doneL && doneR) break;
        if (!doneL && (doneR || dl <= dr)) {
            scan_bin(sp, ofb[bl], ofb[bl + 1], lane, qx, qy, qz, ld, li, tau);
            --bl;
        } else {
            scan_bin(sp, ofb[br], ofb[br + 1], lane, qx, qy, qz, ld, li, tau);
            ++br;
        }
    }

    if (lane < KNN) {
        out_idx[(size_t)g * KNN + lane] = (float)li;
    }
}

// ---------------- fallback: R14 brute-force kernel (measured 141.6 us) ----------------
#define BLOCK 256
#define WPB   4
#define PPL   8
#define ITERS (NPTS / (64 * PPL))   // 64

template <int T>
__device__ __forceinline__ void insert_all(float d, int p, int lane,
                                           float& ld, int& li, float& tau,
                                           float& th, float qnm)
{
    unsigned long long rem = __ballot(d <= tau);
    while (rem) {
        const int srcl = __ffsll(rem) - 1;
        const float wd = readlane_f(d, srcl);
        const int   wi = __builtin_amdgcn_readlane(p, srcl);
        const bool less = (ld < wd) || (ld == wd && li < wi);
        const unsigned long long lm = __ballot(less);
        const int pos = __popc((unsigned)((lm >> (16 * T)) & 0xffffull));
        const float pld = dpp_shr1_f(ld);
        const int   pli = dpp_shr1_i(li);
        if ((lane >> 4) == T) {
            const int gl = lane & 15;
            if (gl == pos)      { ld = wd;  li = wi;  }
            else if (gl > pos)  { ld = pld; li = pli; }
        }
        tau = readlane_f(ld, 16 * T + 15);
        th  = tau + qnm;
        rem &= rem - 1;
        if (rem) rem &= __ballot(d <= tau);
    }
}

__device__ __forceinline__ void load6(float4 dst[6], const float4* p) {
    #pragma unroll
    for (int t = 0; t < 6; ++t) dst[t] = p[t];
}

__device__ __forceinline__ void step2(const float4 c[6], int pb, int lane,
                                      float m2x0, float m2y0, float m2z0,
                                      float m2x1, float m2y1, float m2z1,
                                      float qx0, float qy0, float qz0,
                                      float qx1, float qy1, float qz1,
                                      float& ld, int& li,
                                      float& tau0, float& tau1,
                                      float& th0, float& th1,
                                      float qnm0, float qnm1)
{
    float px[PPL], py[PPL], pz[PPL];
    px[0] = c[0].x; py[0] = c[0].y; pz[0] = c[0].z;
    px[1] = c[0].w; py[1] = c[1].x; pz[1] = c[1].y;
    px[2] = c[1].z; py[2] = c[1].w; pz[2] = c[2].x;
    px[3] = c[2].y; py[3] = c[2].z; pz[3] = c[2].w;
    px[4] = c[3].x; py[4] = c[3].y; pz[4] = c[3].z;
    px[5] = c[3].w; py[5] = c[4].x; pz[5] = c[4].y;
    px[6] = c[4].z; py[6] = c[4].w; pz[6] = c[5].x;
    px[7] = c[5].y; py[7] = c[5].z; pz[7] = c[5].w;

    unsigned long long m0[PPL], m1[PPL], any = 0;
    #pragma unroll
    for (int j = 0; j < PPL; ++j) {
        const float s = __fmaf_rn(pz[j], pz[j],
                          __fmaf_rn(py[j], py[j], __fmul_rn(px[j], px[j])));
        float t0 = __fmaf_rn(px[j], m2x0, s);
        t0 = __fmaf_rn(py[j], m2y0, t0);
        t0 = __fmaf_rn(pz[j], m2z0, t0);
        m0[j] = __ballot(t0 <= th0);
        float t1 = __fmaf_rn(px[j], m2x1, s);
        t1 = __fmaf_rn(py[j], m2y1, t1);
        t1 = __fmaf_rn(pz[j], m2z1, t1);
        m1[j] = __ballot(t1 <= th1);
        any |= m0[j] | m1[j];
    }
    if (any) {
        #pragma unroll
        for (int j = 0; j < PPL; ++j) {
            if (m0[j]) {
                const float dx = __fadd_rn(px[j], -qx0);
                const float dy = __fadd_rn(py[j], -qy0);
                const float dz = __fadd_rn(pz[j], -qz0);
                const float d  = __fadd_rn(
                    __fadd_rn(__fmul_rn(dx, dx), __fmul_rn(dy, dy)),
                    __fmul_rn(dz, dz));
                insert_all<0>(d, pb + j, lane, ld, li, tau0, th0, qnm0);
            }
        }
        #pragma unroll
        for (int j = 0; j < PPL; ++j) {
            if (m1[j]) {
                const float dx = __fadd_rn(px[j], -qx1);
                const float dy = __fadd_rn(py[j], -qy1);
                const float dz = __fadd_rn(pz[j], -qz1);
                const float d  = __fadd_rn(
                    __fadd_rn(__fmul_rn(dx, dx), __fmul_rn(dy, dy)),
                    __fmul_rn(dz, dz));
                insert_all<1>(d, pb + j, lane, ld, li, tau1, th1, qnm1);
            }
        }
    }
}

__global__ __launch_bounds__(BLOCK, 4) void knn_bf(const float* __restrict__ xyz,
                                                   float* __restrict__ out_idx,
                                                   float* __restrict__ out_pts)
{
    const int tid  = threadIdx.x;
    const int lane = tid & 63;
    const int wv   = tid >> 6;
    const int w    = blockIdx.x * WPB + wv;
    const int b    = w >> 10;
    const int pr   = w & 1023;
    const size_t base = (size_t)b * NPTS * 3;

    const int qp0 = pr << 5;
    const float qx0 = xyz[base + 3 * qp0 + 0];
    const float qy0 = xyz[base + 3 * qp0 + 1];
    const float qz0 = xyz[base + 3 * qp0 + 2];
    const float qx1 = xyz[base + 3 * qp0 + 48];
    const float qy1 = xyz[base + 3 * qp0 + 49];
    const float qz1 = xyz[base + 3 * qp0 + 50];

    const int g0 = b * NQ + (pr << 1);
    if (lane == 0) {
        out_pts[3 * g0 + 0] = qx0;
        out_pts[3 * g0 + 1] = qy0;
        out_pts[3 * g0 + 2] = qz0;
        out_pts[3 * g0 + 3] = qx1;
        out_pts[3 * g0 + 4] = qy1;
        out_pts[3 * g0 + 5] = qz1;
    }

    const float m2x0 = -2.0f * qx0, m2y0 = -2.0f * qy0, m2z0 = -2.0f * qz0;
    const float m2x1 = -2.0f * qx1, m2y1 = -2.0f * qy1, m2z1 = -2.0f * qz1;
    const float qnm0 = -(qx0 * qx0 + qy0 * qy0 + qz0 * qz0) + GATE_MARGIN;
    const float qnm1 = -(qx1 * qx1 + qy1 * qy1 + qz1 * qz1) + GATE_MARGIN;

    float ld = __builtin_inff();  int li = 0x7fffffff;
    float tau0 = __builtin_inff(), tau1 = __builtin_inff();
    float th0  = __builtin_inff(), th1  = __builtin_inff();

    const float4* lp0 = (const float4*)(xyz + base) + 6 * lane;

    float4 A[6], Bf[6], Cf[6];
    load6(A,  lp0);
    load6(Bf, lp0 + 384);
    load6(Cf, lp0 + 768);
    const float4* ld_ptr = lp0 + 3 * 384;
    int pb = PPL * lane;

    for (int it = 0; it < 21; ++it) {
        step2(A, pb, lane, m2x0, m2y0, m2z0, m2x1, m2y1, m2z1,
              qx0, qy0, qz0, qx1, qy1, qz1,
              ld, li, tau0, tau1, th0, th1, qnm0, qnm1);
        pb += 512;
        load6(A, ld_ptr);  ld_ptr += 384;
        step2(Bf, pb, lane, m2x0, m2y0, m2z0, m2x1, m2y1, m2z1,
              qx0, qy0, qz0, qx1, qy1, qz1,
              ld, li, tau0, tau1, th0, th1, qnm0, qnm1);
        pb += 512;
        if (it < 20) load6(Bf, ld_ptr);
        ld_ptr += 384;
        step2(Cf, pb, lane, m2x0, m2y0, m2z0, m2x1, m2y1, m2z1,
              qx0, qy0, qz0, qx1, qy1, qz1,
              ld, li, tau0, tau1, th0, th1, qnm0, qnm1);
        pb += 512;
        if (it < 20) load6(Cf, ld_ptr);
        ld_ptr += 384;
    }
    step2(A, pb, lane, m2x0, m2y0, m2z0, m2x1, m2y1, m2z1,
          qx0, qy0, qz0, qx1, qy1, qz1,
          ld, li, tau0, tau1, th0, th1, qnm0, qnm1);

    if (lane < 2 * KNN) {
        out_idx[(size_t)g0 * KNN + lane] = (float)li;
    }
}

extern "C" void kernel_launch(void* const* d_in, const int* in_sizes, int n_in,
                              void* d_out, int out_size, void* d_ws, size_t ws_size,
                              hipStream_t stream) {
    const float* xyz = (const float*)d_in[0];
    float* out = (float*)d_out;
    float* out_idx = out;                                 // NB*NQ*KNN floats
    float* out_pts = out + (size_t)NB * NQ * KNN;         // NB*NQ*3 floats

    const size_t sorted_bytes = (size_t)NB * NPTS * sizeof(float4);   // 2 MB
    const size_t ws_needed = sorted_bytes
                           + (size_t)(NB * (NBINS + 1) + NB * NBINS) * sizeof(int);
    if (d_ws != nullptr && ws_size >= ws_needed) {
        float4* sorted = (float4*)d_ws;
        int* off = (int*)((char*)d_ws + sorted_bytes);
        int* cur = off + NB * (NBINS + 1);
        zero_k<<<NB, NBINS, 0, stream>>>(cur);
        hist_k<<<NB * NPTS / 256, 256, 0, stream>>>(xyz, cur);
        scan_k<<<NB, NBINS, 0, stream>>>(cur, off);
        scatter_k<<<NB * NPTS / 256, 256, 0, stream>>>(xyz, cur, sorted);
        knn_grid<<<NB * NQ / 4, 256, 0, stream>>>(xyz, sorted, off, out_idx, out_pts);
    } else {
        knn_bf<<<(NB * NQ / 2) / WPB, BLOCK, 0, stream>>>(xyz, out_idx, out_pts);
    }
}